// Round 5
// baseline (425.621 us; speedup 1.0000x reference)
//
#include <hip/hip_runtime.h>
#include <hip/hip_bf16.h>
#include <stdint.h>

#define BB 2
#define SS 4096
#define HH 1024
#define NHh 16
#define HD 64
#define LL 64
#define BS 64
#define RR 3
#define PENf (-10000.0f)
// PEN in log2 domain (softmax runs base-2: q is pre-scaled by log2e)
#define PEN2f (-14426.950408889634f)
#define QSCALE (0.125f * 1.44269504088896f)

typedef unsigned int uint;
typedef __attribute__((ext_vector_type(8))) short bf16x8;
typedef __attribute__((ext_vector_type(4))) float f32x4;

__device__ __forceinline__ ushort f2bf(float f) {
    union { float f; uint u; } v; v.f = f;
    uint u = v.u;
    return (ushort)((u + 0x7fffu + ((u >> 16) & 1u)) >> 16);  // RNE
}
__device__ __forceinline__ uint pack_bf(float a, float b) {
    return (uint)f2bf(a) | (((uint)f2bf(b)) << 16);
}
// scale both bf16 halves of a packed uint by QSCALE (rsd * log2e)
__device__ __forceinline__ uint scale_pair(uint w) {
    float lo = __uint_as_float(w << 16) * QSCALE;
    float hi = __uint_as_float(w & 0xffff0000u) * QSCALE;
    return (uint)f2bf(lo) | (((uint)f2bf(hi)) << 16);
}
__device__ __forceinline__ uint4 scale4(uint4 w) {
    uint4 o;
    o.x = scale_pair(w.x); o.y = scale_pair(w.y);
    o.z = scale_pair(w.z); o.w = scale_pair(w.w);
    return o;
}
// async global->LDS, 16B per lane; lds base must be wave-uniform (lane*16 auto)
__device__ __forceinline__ void async16(const ushort* g, ushort* l) {
    __builtin_amdgcn_global_load_lds((const __attribute__((address_space(1))) uint*)g,
                                     (__attribute__((address_space(3))) uint*)l,
                                     16, 0, 0);
}

// ---------------- fp32 -> bf16 convert (X and W), exact grid ----------------
// grid = 13824 blocks x 256: 12288 X-blocks then 1536 W-blocks (uniform branch).
// Also zeroes the dense-combine counters (block 0).
__global__ __launch_bounds__(256)
void cvt_kernel(const float* __restrict__ Xq, const float* __restrict__ Xk,
                const float* __restrict__ Xv, const float* __restrict__ Wq,
                const float* __restrict__ Wk, const float* __restrict__ Wv,
                ushort* __restrict__ Xbf, ushort* __restrict__ Wbf,
                int* __restrict__ ctr)
{
    if (blockIdx.x == 0 && threadIdx.x < 64) ctr[threadIdx.x] = 0;
    const size_t XTOT = (size_t)3 * BB * SS * HH;   // 25165824 = 3 * 2^23
    const uint u = blockIdx.x * 256 + threadIdx.x;
    const size_t e = (size_t)u * 8;
    const float* src; ushort* dst;
    if (e < XTOT) {
        const int zz = (int)(e >> 23);
        src = (zz == 0 ? Xq : zz == 1 ? Xk : Xv) + (e & ((1u << 23) - 1));
        dst = Xbf + e;
    } else {
        const size_t e2 = e - XTOT;
        const int zz = (int)(e2 >> 20);
        src = (zz == 0 ? Wq : zz == 1 ? Wk : Wv) + (e2 & ((1u << 20) - 1));
        dst = Wbf + e2;
    }
    float4 a = ((const float4*)src)[0];
    float4 c = ((const float4*)src)[1];
    uint4 o;
    o.x = pack_bf(a.x, a.y); o.y = pack_bf(a.z, a.w);
    o.z = pack_bf(c.x, c.y); o.w = pack_bf(c.z, c.w);
    *(uint4*)dst = o;
}

// ---------------- m97-style bf16 GEMM, dbuf + swapped epilogue ----------------
__global__ __launch_bounds__(256)
void gemm3_kernel(const ushort* __restrict__ Xbf, const ushort* __restrict__ Wbf,
                  const float* __restrict__ bq, const float* __restrict__ bk,
                  const float* __restrict__ bv,
                  ushort* __restrict__ qb, ushort* __restrict__ kb,
                  ushort* __restrict__ vbT)
{
    __shared__ __align__(16) ushort smem[128 * 136];  // dbuf As/Bs + V restage reuse
    ushort* As = smem;            // [2][128][32]
    ushort* Bs = smem + 8192;     // [2][128][32]

    const int z = blockIdx.z;
    const ushort* A  = Xbf + (size_t)z * ((size_t)BB * SS * HH);
    const ushort* Bt = Wbf + (size_t)z * (HH * HH);
    const float* bias = (z == 0) ? bq : (z == 1) ? bk : bv;

    const int tid = threadIdx.x;
    const int m0 = blockIdx.x * 128;
    const int n0 = blockIdx.y * 128;
    const int wave = tid >> 6;
    const int lane = tid & 63;
    const int l15 = lane & 15;
    const int quad = lane >> 4;
    const int wr = wave >> 1, wc = wave & 1;

    f32x4 acc[4][4];
#pragma unroll
    for (int i = 0; i < 4; ++i)
#pragma unroll
        for (int j = 0; j < 4; ++j) acc[i][j] = (f32x4){0.f, 0.f, 0.f, 0.f};

    const int p8 = (lane & 3) * 8;
    const ushort* Abase = A + (size_t)(m0 + wave * 32 + (lane >> 2)) * HH + p8;
    const ushort* Bbase = Bt + (size_t)(n0 + wave * 32 + (lane >> 2)) * HH + p8;

#define STAGE_G(k0, bp)                                        \
    do {                                                       \
        ushort* A0 = As + (bp) * 4096 + wave * 1024;           \
        ushort* B0 = Bs + (bp) * 4096 + wave * 1024;           \
        async16(Abase + (k0), A0);                             \
        async16(Abase + 16 * HH + (k0), A0 + 512);             \
        async16(Bbase + (k0), B0);                             \
        async16(Bbase + 16 * HH + (k0), B0 + 512);             \
    } while (0)

    STAGE_G(0, 0);
    for (int k0 = 0, bp = 0; k0 < HH; k0 += 32, bp ^= 1) {
        __syncthreads();
        if (k0 + 32 < HH) STAGE_G(k0 + 32, bp ^ 1);
        bf16x8 af[4], bfr[4];
#pragma unroll
        for (int mt = 0; mt < 4; ++mt)
            af[mt] = *(const bf16x8*)(As + bp * 4096 + (wr * 64 + mt * 16 + l15) * 32 + quad * 8);
#pragma unroll
        for (int nt = 0; nt < 4; ++nt)
            bfr[nt] = *(const bf16x8*)(Bs + bp * 4096 + (wc * 64 + nt * 16 + l15) * 32 + quad * 8);
        if (z < 2) {
#pragma unroll
            for (int i = 0; i < 4; ++i)
#pragma unroll
                for (int j = 0; j < 4; ++j)
                    acc[i][j] = __builtin_amdgcn_mfma_f32_16x16x32_bf16(bfr[i], af[j], acc[i][j], 0, 0, 0);
        } else {
#pragma unroll
            for (int i = 0; i < 4; ++i)
#pragma unroll
                for (int j = 0; j < 4; ++j)
                    acc[i][j] = __builtin_amdgcn_mfma_f32_16x16x32_bf16(af[i], bfr[j], acc[i][j], 0, 0, 0);
        }
    }
#undef STAGE_G

    if (z < 2) {
        ushort* outp = (z == 0) ? qb : kb;
#pragma unroll
        for (int wt = 0; wt < 4; ++wt) {
            const int n_base = n0 + wc * 64 + wt * 16 + quad * 4;
            const float4 b4 = *(const float4*)&bias[n_base];
            const int nh = n_base >> 6;
            const int hd = n_base & 63;
#pragma unroll
            for (int xt = 0; xt < 4; ++xt) {
                const int m = m0 + wr * 64 + xt * 16 + l15;
                const int bgl = m >> 12, s = m & 4095;
                uint2 pk;
                pk.x = pack_bf(acc[wt][xt][0] + b4.x, acc[wt][xt][1] + b4.y);
                pk.y = pack_bf(acc[wt][xt][2] + b4.z, acc[wt][xt][3] + b4.w);
                *(uint2*)&outp[((size_t)((bgl << 4) | nh) * SS + s) * HD + hd] = pk;
            }
        }
    } else {
        __syncthreads();
        ushort* stg = smem;  // [128 n][136 m]
#pragma unroll
        for (int nt = 0; nt < 4; ++nt) {
            const int n_local = wc * 64 + nt * 16 + l15;
            const float bn = bias[n0 + n_local];
#pragma unroll
            for (int mt = 0; mt < 4; ++mt) {
                const int m_base = wr * 64 + mt * 16 + quad * 4;
                uint2 pk;
                pk.x = pack_bf(acc[mt][nt][0] + bn, acc[mt][nt][1] + bn);
                pk.y = pack_bf(acc[mt][nt][2] + bn, acc[mt][nt][3] + bn);
                *(uint2*)(stg + n_local * 136 + m_base) = pk;
            }
        }
        __syncthreads();
        const int n_row = tid >> 1;
        const int half = tid & 1;
        const int n = n0 + n_row;
        const int nh = n >> 6, hd = n & 63;
        const int bgl = m0 >> 12;
        const int sbase = (m0 & 4095) + half * 64;
        const uint4* src = (const uint4*)(stg + n_row * 136 + half * 64);
        uint4* dst = (uint4*)(vbT + ((size_t)((bgl << 4) | nh) * HD + hd) * SS + sbase);
#pragma unroll
        for (int j = 0; j < 8; ++j) dst[j] = src[j];
    }
}

// ---------------- R1 fallback projection (inline convert) ----------------
__global__ __launch_bounds__(256)
void proj3_kernel(const float* __restrict__ Xq, const float* __restrict__ Xk,
                  const float* __restrict__ Xv,
                  const float* __restrict__ Wq, const float* __restrict__ Wk,
                  const float* __restrict__ Wv,
                  const float* __restrict__ bq, const float* __restrict__ bk,
                  const float* __restrict__ bv,
                  ushort* __restrict__ qb, ushort* __restrict__ kb,
                  ushort* __restrict__ vbT)
{
    __shared__ __align__(16) ushort smem[128 * 136];
    ushort* As = smem;             // [128][40]
    ushort* Bs = smem + 128 * 40;  // [128][40]

    const int z = blockIdx.z;
    const float* X    = (z == 0) ? Xq : (z == 1) ? Xk : Xv;
    const float* W    = (z == 0) ? Wq : (z == 1) ? Wk : Wv;
    const float* bias = (z == 0) ? bq : (z == 1) ? bk : bv;

    const int tid = threadIdx.x;
    const int m0 = blockIdx.x * 128;
    const int n0 = blockIdx.y * 128;
    const int wave = tid >> 6;
    const int lane = tid & 63;
    const int l15 = lane & 15;
    const int quad = lane >> 4;
    const int wr = wave >> 1, wc = wave & 1;

    f32x4 acc[4][4];
#pragma unroll
    for (int mt = 0; mt < 4; ++mt)
#pragma unroll
        for (int nt = 0; nt < 4; ++nt) acc[mt][nt] = (f32x4){0.f, 0.f, 0.f, 0.f};

    const int srow = tid >> 1;
    const int shalf = tid & 1;
    const float* xp = X + (size_t)(m0 + srow) * HH + shalf * 16;
    const float* wp = W + (size_t)(n0 + srow) * HH + shalf * 16;
    ushort* asw = As + srow * 40 + shalf * 16;
    ushort* bsw = Bs + srow * 40 + shalf * 16;

    for (int k0 = 0; k0 < HH; k0 += 32) {
        float4 a0 = *(const float4*)(xp + k0);
        float4 a1 = *(const float4*)(xp + k0 + 4);
        float4 a2 = *(const float4*)(xp + k0 + 8);
        float4 a3 = *(const float4*)(xp + k0 + 12);
        float4 b0 = *(const float4*)(wp + k0);
        float4 b1 = *(const float4*)(wp + k0 + 4);
        float4 b2 = *(const float4*)(wp + k0 + 8);
        float4 b3 = *(const float4*)(wp + k0 + 12);
        __syncthreads();
        uint4 pa, pb;
        pa.x = pack_bf(a0.x, a0.y); pa.y = pack_bf(a0.z, a0.w);
        pa.z = pack_bf(a1.x, a1.y); pa.w = pack_bf(a1.z, a1.w);
        *(uint4*)asw = pa;
        pa.x = pack_bf(a2.x, a2.y); pa.y = pack_bf(a2.z, a2.w);
        pa.z = pack_bf(a3.x, a3.y); pa.w = pack_bf(a3.z, a3.w);
        *(uint4*)(asw + 8) = pa;
        pb.x = pack_bf(b0.x, b0.y); pb.y = pack_bf(b0.z, b0.w);
        pb.z = pack_bf(b1.x, b1.y); pb.w = pack_bf(b1.z, b1.w);
        *(uint4*)bsw = pb;
        pb.x = pack_bf(b2.x, b2.y); pb.y = pack_bf(b2.z, b2.w);
        pb.z = pack_bf(b3.x, b3.y); pb.w = pack_bf(b3.z, b3.w);
        *(uint4*)(bsw + 8) = pb;
        __syncthreads();

        bf16x8 af[4], bfr[4];
#pragma unroll
        for (int mt = 0; mt < 4; ++mt)
            af[mt] = *(const bf16x8*)(As + (wr * 64 + mt * 16 + l15) * 40 + quad * 8);
#pragma unroll
        for (int nt = 0; nt < 4; ++nt)
            bfr[nt] = *(const bf16x8*)(Bs + (wc * 64 + nt * 16 + l15) * 40 + quad * 8);
#pragma unroll
        for (int mt = 0; mt < 4; ++mt)
#pragma unroll
            for (int nt = 0; nt < 4; ++nt)
                acc[mt][nt] = __builtin_amdgcn_mfma_f32_16x16x32_bf16(af[mt], bfr[nt], acc[mt][nt], 0, 0, 0);
    }

    if (z < 2) {
        ushort* outp = (z == 0) ? qb : kb;
#pragma unroll
        for (int nt = 0; nt < 4; ++nt) {
            const int n = n0 + wc * 64 + nt * 16 + l15;
            const float bn = bias[n];
            const int nh = n >> 6, hd = n & 63;
#pragma unroll
            for (int mt = 0; mt < 4; ++mt) {
#pragma unroll
                for (int rr = 0; rr < 4; ++rr) {
                    const int m = m0 + wr * 64 + mt * 16 + quad * 4 + rr;
                    const int bgl = m >> 12, s = m & 4095;
                    outp[((size_t)((bgl << 4) | nh) * SS + s) * HD + hd] = f2bf(acc[mt][nt][rr] + bn);
                }
            }
        }
    } else {
        __syncthreads();
        ushort* stg = smem;
#pragma unroll
        for (int nt = 0; nt < 4; ++nt) {
            const int n_local = wc * 64 + nt * 16 + l15;
            const float bn = bias[n0 + n_local];
#pragma unroll
            for (int mt = 0; mt < 4; ++mt) {
                const int m_base = wr * 64 + mt * 16 + quad * 4;
                uint2 pk;
                pk.x = pack_bf(acc[mt][nt][0] + bn, acc[mt][nt][1] + bn);
                pk.y = pack_bf(acc[mt][nt][2] + bn, acc[mt][nt][3] + bn);
                *(uint2*)(stg + n_local * 136 + m_base) = pk;
            }
        }
        __syncthreads();
        const int n_row = tid >> 1;
        const int half = tid & 1;
        const int n = n0 + n_row;
        const int nh = n >> 6, hd = n & 63;
        const int bgl = m0 >> 12;
        const int sbase = (m0 & 4095) + half * 64;
        const uint4* src = (const uint4*)(stg + n_row * 136 + half * 64);
        uint4* dst = (uint4*)(vbT + ((size_t)((bgl << 4) | nh) * HD + hd) * SS + sbase);
#pragma unroll
        for (int j = 0; j < 8; ++j) dst[j] = src[j];
    }
}

// ---------------- block-sparse attention: S^T, log2-softmax, MFMA row-sum ----------------
// qg/kg bf16 [bh][s][d]; vTg bf16 [bh][d][s]; out f32 [b][s][h*d].
__global__ __launch_bounds__(256)
void attn_kernel(const ushort* __restrict__ qg, const ushort* __restrict__ kg,
                 const ushort* __restrict__ vTg,
                 const float* __restrict__ mask, const int* __restrict__ rand_attn,
                 float* __restrict__ out, float* __restrict__ partO,
                 float* __restrict__ partML, int* __restrict__ ctr, int fused)
{
    __shared__ __align__(16) ushort qs_ps[64][72];      // q staging, then ps (wave-private bands)
    __shared__ __align__(16) ushort ks2[2][2][64][32];  // [buf][k-chunk][kc][d32]
    __shared__ __align__(16) ushort vs2[2][2][64][32];  // [buf][kc-chunk][d][kc32]
    __shared__ __align__(16) float qm_s[64];
    __shared__ __align__(16) float km_s[2][64];

    const int tid = threadIdx.x;
    const int wid = blockIdx.x;
    const int bh = wid / 78;
    const int r = wid - bh * 78;
    const int b = bh >> 4, h = bh & 15;

    int i, nkb;
    int kbl[8], pfl[8];
    bool dense;
    int part = 0, which = 0;
    if (r < 62) {
        dense = false;
        i = r + 1;
        const int* ra = rand_attn + ((size_t)h * (LL - 2) + (i - 1)) * RR;
        if (i == 1) {
            kbl[0] = 0; kbl[1] = 1; kbl[2] = 2; kbl[3] = LL - 1;
            kbl[4] = ra[0]; kbl[5] = ra[1]; kbl[6] = ra[2]; kbl[7] = 0;
            pfl[0] = pfl[1] = pfl[2] = pfl[3] = 0;
            pfl[4] = pfl[5] = pfl[6] = 1; pfl[7] = 0;
            nkb = 7;
        } else if (i == LL - 2) {
            kbl[0] = 0; kbl[1] = LL - 3; kbl[2] = LL - 2; kbl[3] = LL - 1;
            kbl[4] = ra[0]; kbl[5] = ra[1]; kbl[6] = ra[2]; kbl[7] = 0;
            pfl[0] = pfl[1] = pfl[2] = pfl[3] = 0;
            pfl[4] = pfl[5] = pfl[6] = 1; pfl[7] = 0;
            nkb = 7;
        } else {
            kbl[0] = 0;      pfl[0] = 0;
            kbl[1] = i - 1;  pfl[1] = 1;
            kbl[2] = i;      pfl[2] = 1;
            kbl[3] = i + 1;  pfl[3] = 1;
            kbl[4] = LL - 1; pfl[4] = 0;
            kbl[5] = ra[0]; kbl[6] = ra[1]; kbl[7] = ra[2];
            pfl[5] = pfl[6] = pfl[7] = 1;
            nkb = 8;
        }
    } else {
        dense = true;
        const int r2 = r - 62;
        which = r2 >> 3;
        part = r2 & 7;
        i = which ? (LL - 1) : 0;
        nkb = 8;
#pragma unroll
        for (int j = 0; j < 8; ++j) { kbl[j] = part * 8 + j; pfl[j] = 0; }
    }

    const int lane = tid & 63;
    const int wave = tid >> 6;
    const int l15 = lane & 15;
    const int quad = lane >> 4;
    const int srow = lane >> 2;
    const int p8 = (lane & 3) * 8;
    const ushort* kgb = kg + (size_t)bh * SS * HD;
    const ushort* vgb = vTg + (size_t)bh * HD * SS;

#define STAGE_KV(kb_, bp)                                                        \
    do {                                                                         \
        const size_t krow = (size_t)((kb_) * BS + wave * 16 + srow) * HD;        \
        async16(kgb + krow + p8,      &ks2[bp][0][wave * 16][0]);                \
        async16(kgb + krow + 32 + p8, &ks2[bp][1][wave * 16][0]);                \
        const size_t vrow = (size_t)(wave * 16 + srow) * SS + (kb_) * BS;        \
        async16(vgb + vrow + p8,      &vs2[bp][0][wave * 16][0]);                \
        async16(vgb + vrow + 32 + p8, &vs2[bp][1][wave * 16][0]);                \
    } while (0)

    // stage q (scaled by rsd*log2e) + masks + first K/V buffer
    {
        const int row = tid >> 2;
        const int c0 = (tid & 3) * 16;
        const ushort* src = qg + ((size_t)bh * SS + i * BS + row) * HD + c0;
        uint4 w0 = *(const uint4*)src;
        uint4 w1 = *(const uint4*)(src + 8);
        *(uint4*)&qs_ps[row][c0] = scale4(w0);
        *(uint4*)&qs_ps[row][c0 + 8] = scale4(w1);
        if (tid < 64) qm_s[tid] = mask[(size_t)b * SS + i * BS + tid];
    }
    STAGE_KV(kbl[0], 0);
    if (tid < 64) km_s[0][tid] = mask[(size_t)b * SS + kbl[0] * BS + tid];
    __syncthreads();  // publish qs, buf0, masks

    // hoist q fragments (B-operand, n=q=wave*16+l15); qs region becomes ps after this
    bf16x8 aq[2];
    aq[0] = *(const bf16x8*)&qs_ps[wave * 16 + l15][quad * 8];
    aq[1] = *(const bf16x8*)&qs_ps[wave * 16 + l15][32 + quad * 8];
    const float qm = qm_s[wave * 16 + l15];
    const float a_pf = qm * (-PEN2f);   // product penalty slope
    const float a_nf = -PEN2f;          // key-only penalty slope

    // ones B-fragment: B[n][k] = 1 iff n==0 -> D col 0 = row-sum of P
    bf16x8 ones;
    {
        const short ob = (l15 == 0) ? (short)0x3F80 : (short)0;
#pragma unroll
        for (int j = 0; j < 8; ++j) ones[j] = ob;
    }

    float mrow = -1e30f;   // per-lane running max (log2 domain), q = wave*16 + l15
    f32x4 accO[4];
    f32x4 accL = (f32x4){0.f, 0.f, 0.f, 0.f};
#pragma unroll
    for (int dt = 0; dt < 4; ++dt) accO[dt] = (f32x4){0.f, 0.f, 0.f, 0.f};

    for (int it = 0; it < nkb; ++it) {
        const int cur = it & 1;
        if (it + 1 < nkb) {
            STAGE_KV(kbl[it + 1], cur ^ 1);
            if (tid < 64) km_s[cur ^ 1][tid] = mask[(size_t)b * SS + kbl[it + 1] * BS + tid];
        }
        const int pf = pfl[it];

        // S^T = K . Q^T, accumulator pre-biased with PEN2
        f32x4 sc[4];
#pragma unroll
        for (int nt = 0; nt < 4; ++nt) sc[nt] = (f32x4){PEN2f, PEN2f, PEN2f, PEN2f};
#pragma unroll
        for (int c = 0; c < 2; ++c) {
#pragma unroll
            for (int nt = 0; nt < 4; ++nt) {
                bf16x8 af = *(const bf16x8*)&ks2[cur][c][nt * 16 + l15][quad * 8];
                sc[nt] = __builtin_amdgcn_mfma_f32_16x16x32_bf16(af, aq[c], sc[nt], 0, 0, 0);
            }
        }

        // penalty: sv = s + PEN2 + a*km  (a = pf ? -PEN2*qm : -PEN2); one fma/score
        const float a = pf ? a_pf : a_nf;
        float p[4][4];
        float bm = -1e30f;
#pragma unroll
        for (int nt = 0; nt < 4; ++nt) {
            const float4 km4 = *(const float4*)&km_s[cur][nt * 16 + quad * 4];
            const float kmv[4] = {km4.x, km4.y, km4.z, km4.w};
#pragma unroll
            for (int rr = 0; rr < 4; ++rr) {
                const float sv = fmaf(a, kmv[rr], sc[nt][rr]);
                p[nt][rr] = sv;
                bm = fmaxf(bm, sv);
            }
        }
        bm = fmaxf(bm, __shfl_xor(bm, 16));
        bm = fmaxf(bm, __shfl_xor(bm, 32));
        const float mn = fmaxf(mrow, bm);
        const float alpha = exp2f(mrow - mn);
        mrow = mn;
#pragma unroll
        for (int nt = 0; nt < 4; ++nt)
#pragma unroll
            for (int rr = 0; rr < 4; ++rr)
                p[nt][rr] = exp2f(p[nt][rr] - mn);

        // write P (bf16) into wave-private ps rows; b64 stores
#pragma unroll
        for (int nt = 0; nt < 4; ++nt) {
            uint2 pk;
            pk.x = pack_bf(p[nt][0], p[nt][1]);
            pk.y = pack_bf(p[nt][2], p[nt][3]);
            *(uint2*)&qs_ps[wave * 16 + l15][nt * 16 + quad * 4] = pk;
        }
        // broadcast alpha to acc row domain (q_local = quad*4+rr), rescale O and L
        float a4[4];
#pragma unroll
        for (int rr = 0; rr < 4; ++rr) a4[rr] = __shfl(alpha, quad * 4 + rr, 64);
#pragma unroll
        for (int rr = 0; rr < 4; ++rr) accL[rr] *= a4[rr];
#pragma unroll
        for (int dt = 0; dt < 4; ++dt) {
#pragma unroll
            for (int rr = 0; rr < 4; ++rr) accO[dt][rr] *= a4[rr];
        }

        // PV + row-sum: A = ps (m=q); B = vs2 (n=d) and ones (n==0 -> l)
#pragma unroll
        for (int c = 0; c < 2; ++c) {
            bf16x8 ap = *(const bf16x8*)&qs_ps[wave * 16 + l15][c * 32 + quad * 8];
            accL = __builtin_amdgcn_mfma_f32_16x16x32_bf16(ap, ones, accL, 0, 0, 0);
#pragma unroll
            for (int dt = 0; dt < 4; ++dt) {
                bf16x8 bvf = *(const bf16x8*)&vs2[cur][c][dt * 16 + l15][quad * 8];
                accO[dt] = __builtin_amdgcn_mfma_f32_16x16x32_bf16(ap, bvf, accO[dt], 0, 0, 0);
            }
        }

        if (it + 1 < nkb) __syncthreads();
    }
#undef STAGE_KV

    if (!dense) {
        // accL col 0 (l15==0 lanes) holds l for q_local = quad*4+rr
#pragma unroll
        for (int rr = 0; rr < 4; ++rr) {
            const int qloc = quad * 4 + rr;
            const float lq = __shfl(accL[rr], quad << 4, 64);
            const float inv = qm_s[wave * 16 + qloc] / lq;
#pragma unroll
            for (int dt = 0; dt < 4; ++dt) {
                const int d = dt * 16 + l15;
                out[((size_t)b * SS + i * BS + wave * 16 + qloc) * HH + h * HD + d] = accO[dt][rr] * inv;
            }
        }
    } else {
        const int g = bh * 2 + which;
        const int slot = g * 8 + part;
        float* po = partO + (size_t)slot * 4096;
#pragma unroll
        for (int rr = 0; rr < 4; ++rr) {
            const int qrow = wave * 16 + quad * 4 + rr;
#pragma unroll
            for (int dt = 0; dt < 4; ++dt) {
                const int d = dt * 16 + l15;
                po[qrow * 64 + d] = accO[dt][rr];
            }
        }
        if (l15 == 0) {
#pragma unroll
            for (int rr = 0; rr < 4; ++rr)
                partML[slot * 128 + 64 + wave * 16 + quad * 4 + rr] = accL[rr];
        }
        if (lane < 16)
            partML[slot * 128 + wave * 16 + lane] = mrow;   // log2 domain

        if (fused) {
            __threadfence();   // release partials
            __shared__ int last;
            if (tid == 0) last = (atomicAdd(&ctr[g], 1) == 7);
            __syncthreads();
            if (last) {
                __threadfence();   // acquire all 8 partials
                const int row = tid >> 2;
                const int d0 = (tid & 3) * 16;
                const int base = g * 8;
                float mp[8], lp[8];
                float M = -1e30f;
#pragma unroll
                for (int p2 = 0; p2 < 8; ++p2) {
                    mp[p2] = partML[(base + p2) * 128 + row];
                    lp[p2] = partML[(base + p2) * 128 + 64 + row];
                    M = fmaxf(M, mp[p2]);
                }
                float L = 0.0f, w[8];
#pragma unroll
                for (int p2 = 0; p2 < 8; ++p2) { w[p2] = exp2f(mp[p2] - M); L += lp[p2] * w[p2]; }
                float4 o[4];
#pragma unroll
                for (int j = 0; j < 4; ++j) o[j] = make_float4(0.f, 0.f, 0.f, 0.f);
#pragma unroll
                for (int p2 = 0; p2 < 8; ++p2) {
                    const float* pp = partO + (size_t)(base + p2) * 4096 + row * 64 + d0;
#pragma unroll
                    for (int j = 0; j < 4; ++j) {
                        float4 v = *(const float4*)(pp + j * 4);
                        o[j].x = fmaf(w[p2], v.x, o[j].x);
                        o[j].y = fmaf(w[p2], v.y, o[j].y);
                        o[j].z = fmaf(w[p2], v.z, o[j].z);
                        o[j].w = fmaf(w[p2], v.w, o[j].w);
                    }
                }
                const float fm = mask[(size_t)b * SS + i * BS + row];
                const float inv = fm / L;
                float* dst = out + ((size_t)b * SS + i * BS + row) * HH + h * HD + d0;
#pragma unroll
                for (int j = 0; j < 4; ++j) {
                    float4 v;
                    v.x = o[j].x * inv; v.y = o[j].y * inv;
                    v.z = o[j].z * inv; v.w = o[j].w * inv;
                    *(float4*)(dst + j * 4) = v;
                }
            }
        }
    }
}

// ---------------- combine partials (fallback path only) ----------------
__global__ __launch_bounds__(256)
void combine_kernel(const float* __restrict__ partO, const float* __restrict__ partML,
                    const float* __restrict__ mask, float* __restrict__ out)
{
    const int g = blockIdx.x;
    const int bh = g >> 1, which = g & 1;
    const int b = bh >> 4, h = bh & 15;
    const int i = which ? (LL - 1) : 0;
    const int t = threadIdx.x;
    const int row = t >> 2;
    const int d0 = (t & 3) * 16;
    const int base = g * 8;

    float mp[8], lp[8];
    float M = -1e30f;
#pragma unroll
    for (int p = 0; p < 8; ++p) {
        mp[p] = partML[(base + p) * 128 + row];
        lp[p] = partML[(base + p) * 128 + 64 + row];
        M = fmaxf(M, mp[p]);
    }
    float L = 0.0f, w[8];
#pragma unroll
    for (int p = 0; p < 8; ++p) { w[p] = exp2f(mp[p] - M); L += lp[p] * w[p]; }

    float4 o[4];
#pragma unroll
    for (int j = 0; j < 4; ++j) o[j] = make_float4(0.f, 0.f, 0.f, 0.f);
#pragma unroll
    for (int p = 0; p < 8; ++p) {
        const float* po = partO + (size_t)(base + p) * 4096 + row * 64 + d0;
#pragma unroll
        for (int j = 0; j < 4; ++j) {
            float4 v = *(const float4*)(po + j * 4);
            o[j].x = fmaf(w[p], v.x, o[j].x);
            o[j].y = fmaf(w[p], v.y, o[j].y);
            o[j].z = fmaf(w[p], v.z, o[j].z);
            o[j].w = fmaf(w[p], v.w, o[j].w);
        }
    }
    const float fm = mask[(size_t)b * SS + i * BS + row];
    const float inv = fm / L;
    float* dst = out + ((size_t)b * SS + i * BS + row) * HH + h * HD + d0;
#pragma unroll
    for (int j = 0; j < 4; ++j) {
        float4 v;
        v.x = o[j].x * inv; v.y = o[j].y * inv;
        v.z = o[j].z * inv; v.w = o[j].w * inv;
        *(float4*)(dst + j * 4) = v;
    }
}

extern "C" void kernel_launch(void* const* d_in, const int* in_sizes, int n_in,
                              void* d_out, int out_size, void* d_ws, size_t ws_size,
                              hipStream_t stream) {
    (void)in_sizes; (void)n_in; (void)out_size;
    const float* Q    = (const float*)d_in[0];
    const float* K    = (const float*)d_in[1];
    const float* V    = (const float*)d_in[2];
    const float* mask = (const float*)d_in[3];
    const float* Wq   = (const float*)d_in[4];
    const float* bq   = (const float*)d_in[5];
    const float* Wk   = (const float*)d_in[6];
    const float* bk   = (const float*)d_in[7];
    const float* Wv   = (const float*)d_in[8];
    const float* bv   = (const float*)d_in[9];
    const int*   ra   = (const int*)d_in[10];
    float* out = (float*)d_out;

    const size_t qkv = (size_t)BB * NHh * SS * HD;  // 8388608 elems
    ushort* qb  = (ushort*)d_ws;
    ushort* kb  = qb + qkv;
    ushort* vbT = kb + qkv;
    float* partO  = (float*)(vbT + qkv);            // 512 * 4096 f32
    float* partML = partO + (size_t)512 * 4096;     // 512 * 128 f32
    int* ctr = (int*)(partML + (size_t)512 * 128);  // 64 ints
    ushort* Xbf = (ushort*)(ctr + 64);
    ushort* Wbf = Xbf + 3 * qkv;
    const size_t need = (size_t)((char*)(Wbf + (size_t)3 * HH * HH) - (char*)d_ws);

    if (ws_size >= need) {
        cvt_kernel<<<13824, 256, 0, stream>>>(Q, K, V, Wq, Wk, Wv, Xbf, Wbf, ctr);
        gemm3_kernel<<<dim3(64, 8, 3), 256, 0, stream>>>(Xbf, Wbf, bq, bk, bv, qb, kb, vbT);
        attn_kernel<<<dim3(BB * NHh * 78), 256, 0, stream>>>(qb, kb, vbT, mask, ra,
                                                             out, partO, partML, ctr, 1);
    } else {
        proj3_kernel<<<dim3(64, 8, 3), 256, 0, stream>>>(Q, K, V, Wq, Wk, Wv, bq, bk, bv,
                                                         qb, kb, vbT);
        attn_kernel<<<dim3(BB * NHh * 78), 256, 0, stream>>>(qb, kb, vbT, mask, ra,
                                                             out, partO, partML, ctr, 0);
        combine_kernel<<<dim3(BB * NHh * 2), 256, 0, stream>>>(partO, partML, mask, out);
    }
}